// Round 16
// baseline (59.756 us; speedup 1.0000x reference)
//
#include <hip/hip_runtime.h>

// B=256, N=512 cells, G=117 genes, CH=25 conv channels.
// One block = one batch (512 cells), 1024 threads = 16 waves (4/SIMD - double
// the store/MFMA concurrency of all prior rounds); wave owns 32 cells x all
// 128 genes (acc = 4 x f32x16 = 64 VGPR). Conv-as-MFMA with register handoff
// (cvt_pk + permlane32_swap) into the regression MFMAs.
// ZERO-BARRIER K LOOP: weights read per-wave from prep'd wcomb (L1 broadcast).
// out1 streamed during the loop; spot from registers (one barrier); cell
// stored directly from accumulators. Numerics identical to r13/r15 (absmax 8).

typedef __attribute__((ext_vector_type(16))) float f32x16;
typedef __attribute__((ext_vector_type(8))) short short8;
typedef __attribute__((ext_vector_type(2))) unsigned int uint2v;
typedef __attribute__((ext_vector_type(4))) unsigned int uint4v;

#define WCOMB_OFF 0          // 245760 B : [20 jt][12288 B = 4KB a | 8KB wb]
#define GLOB_OFF  245760     // 1024 B   : glob[256]

#define SPOT_OUT_OFF 0
#define CELL_OUT_OFF 29952
#define OUT1_OUT_OFF 15365376

__device__ __forceinline__ unsigned short f2bf(float x) {
  unsigned int u = __builtin_bit_cast(unsigned int, x);
  u = (u + 0x7FFFu + ((u >> 16) & 1u)) >> 16;   // RNE
  return (unsigned short)u;
}

__device__ __forceinline__ unsigned int cvt_pk_bf16(float lo, float hi) {
  unsigned int w;
  asm("v_cvt_pk_bf16_f32 %0, %1, %2" : "=v"(w) : "v"(lo), "v"(hi));
  return w;
}

// blocks 0..255: glob ; 256..335: a-frags (jt x s) ; 336..495: wb (sg x q)
__global__ __launch_bounds__(128) void prep_kernel(
    const float* __restrict__ spot_images, const float* __restrict__ W_patch,
    const float* __restrict__ b_patch, const float* __restrict__ W_glob,
    const float* __restrict__ b_glob, const float* __restrict__ W_reg,
    const float* __restrict__ W_emph, const float* __restrict__ b_emph,
    unsigned short* __restrict__ wcomb, float* __restrict__ glob) {
  int bid = blockIdx.x;
  int tid = threadIdx.x;
  if (bid < 256) {
    __shared__ float red[75];
    if (tid < 75) {
      int token = tid / 3;
      int chan = tid - token * 3;
      int ty = token / 5, tx = token - ty * 5;
      const float* img = spot_images + bid * 784 + (ty * 5) * 28 + tx * 5;
      float a = 0.f;
      #pragma unroll
      for (int i = 0; i < 5; ++i)
        #pragma unroll
        for (int j = 0; j < 5; ++j)
          a = fmaf(img[i * 28 + j], W_patch[chan * 25 + i * 5 + j], a);
      a += b_patch[chan];
      red[tid] = a * W_glob[tid];
    }
    __syncthreads();
    if (tid == 0) {
      float s = b_glob[0];
      for (int k = 0; k < 75; ++k) s += red[k];
      glob[bid] = (s > 0.f) ? s : expm1f(s);
    }
  } else if (bid < 336) {
    int idx = bid - 256;               // jt*4 + s
    int jt = idx >> 2, s = idx & 3;
    if (tid < 64) {
      int j = jt * 32 + (tid & 31);
      int h = tid >> 5;
      unsigned short hv[8];
      #pragma unroll
      for (int jj = 0; jj < 8; ++jj) {
        int i = s * 16 + h * 8 + jj;
        float val = 0.f;
        if (j < 625) {
          int ch = j / 25, p = j % 25;
          int oy = p / 5, ox = p - oy * 5;
          if (i < 49) {
            int iy = i / 7, ix = i - iy * 7;
            int ky = iy - oy, kx = ix - ox;
            if (ky >= 0 && ky < 3 && kx >= 0 && kx < 3)
              val = W_emph[ch * 9 + ky * 3 + kx];
          } else if (i == 49) {
            val = b_emph[ch];
          }
        }
        hv[jj] = f2bf(val);
      }
      unsigned int u[4];
      #pragma unroll
      for (int k = 0; k < 4; ++k)
        u[k] = (unsigned int)hv[2 * k] | ((unsigned int)hv[2 * k + 1] << 16);
      ((uint4*)wcomb)[jt * 768 + s * 64 + tid] = make_uint4(u[0], u[1], u[2], u[3]);
    }
  } else {
    int idx = bid - 336;               // sg*4 + q   (sg = kstep 0..39)
    int sg = idx >> 2, q = idx & 3;
    if (tid < 64) {
      int g = q * 32 + (tid & 31);
      int h = tid >> 5;
      unsigned short hv[8];
      #pragma unroll
      for (int jj = 0; jj < 8; ++jj) {
        int k = sg * 16 + h * 8 + jj;
        float val = (g < 117 && k < 625) ? W_reg[g * 625 + k] : 0.f;
        hv[jj] = f2bf(val);
      }
      unsigned int u[4];
      #pragma unroll
      for (int k = 0; k < 4; ++k)
        u[k] = (unsigned int)hv[2 * k] | ((unsigned int)hv[2 * k + 1] << 16);
      int jt = sg >> 1, c = (sg & 1) * 4 + q;   // chunk c = ks*4 + q
      ((uint4*)wcomb)[jt * 768 + 256 + c * 64 + tid] =
          make_uint4(u[0], u[1], u[2], u[3]);
    }
  }
}

// One block = batch b (512 cells). 1024 threads = 16 waves (wct = 32-cell group).
__global__ __launch_bounds__(1024, 4) void main_kernel(
    const float* __restrict__ images, const float* __restrict__ b_reg,
    const unsigned short* __restrict__ wcomb, const float* __restrict__ glob,
    float* __restrict__ out) {
  __shared__ unsigned short imgbs[8 * 512 * 8];   // 65536 B
  __shared__ float redp[16 * 128];                // 8192 B
  int tid = threadIdx.x;
  int b = blockIdx.x;
  int l = tid & 63;
  int wct = __builtin_amdgcn_readfirstlane(tid >> 6);   // wave 0..15
  int m = l & 31, hh = l >> 5;
  const short8* imgb8 = (const short8*)imgbs;
  const short8* wc8 = (const short8*)wcomb;   // [jt*768 + frag*64 + lane]

  float gb = glob[b];
  size_t rowbase = (size_t)b * 512;
  float4 gv = make_float4(gb, gb, gb, gb);
  float4* o1v = (float4*)(out + OUT1_OUT_OFF + rowbase * 117);  // 14976 float4

  // ---- stage all 512 cells of img -> bf16 chunk-major LDS ----
  #pragma unroll
  for (int it = 0; it < 4; ++it) {
    int u = it * 1024 + tid;
    int cell = u & 511, kc = u >> 9;
    const float* src = images + (size_t)(b * 512 + cell) * 49 + kc * 8;
    float v[8];
    #pragma unroll
    for (int j = 0; j < 8; ++j) v[j] = 0.f;
    if (kc < 6) {
      #pragma unroll
      for (int j = 0; j < 8; ++j) v[j] = src[j];
    } else if (kc == 6) {
      v[0] = src[0];
      v[1] = 1.0f;
    }
    unsigned int uu[4];
    #pragma unroll
    for (int k = 0; k < 4; ++k) uu[k] = cvt_pk_bf16(v[2 * k], v[2 * k + 1]);
    ((uint4*)imgbs)[kc * 512 + cell] = make_uint4(uu[0], uu[1], uu[2], uu[3]);
  }
  __syncthreads();

  // persistent img B-frags for this wave's 32 cells
  short8 bF0 = imgb8[(0 + hh) * 512 + wct * 32 + m];
  short8 bF1 = imgb8[(2 + hh) * 512 + wct * 32 + m];
  short8 bF2 = imgb8[(4 + hh) * 512 + wct * 32 + m];
  short8 bF3 = imgb8[(6 + hh) * 512 + wct * 32 + m];
  // NOTE: no further barriers until the spot reduction.

  f32x16 acc0, acc1, acc2, acc3;
  #pragma unroll
  for (int i = 0; i < 16; ++i) {
    acc0[i] = 0.f; acc1[i] = 0.f; acc2[i] = 0.f; acc3[i] = 0.f;
  }

  for (int jt = 0; jt < 20; ++jt) {
    if (jt < 15) {                              // out1 stream during compute
      int i0 = jt * 1024 + tid;
      if (i0 < 14976) o1v[i0] = gv;
    }
    // weights straight from global (L1 broadcast across the 16 waves)
    const short8* wB = wc8 + jt * 768;
    short8 a0 = wB[l];
    short8 a1 = wB[64 + l];
    short8 a2 = wB[128 + l];
    short8 a3 = wB[192 + l];

    // conv then pack
    f32x16 o;
    #pragma unroll
    for (int i = 0; i < 16; ++i) o[i] = 0.f;
    o = __builtin_amdgcn_mfma_f32_32x32x16_bf16(a0, bF0, o, 0, 0, 0);
    o = __builtin_amdgcn_mfma_f32_32x32x16_bf16(a1, bF1, o, 0, 0, 0);
    o = __builtin_amdgcn_mfma_f32_32x32x16_bf16(a2, bF2, o, 0, 0, 0);
    o = __builtin_amdgcn_mfma_f32_32x32x16_bf16(a3, bF3, o, 0, 0, 0);
    unsigned int W[8];
    #pragma unroll
    for (int q = 0; q < 8; ++q)
      W[q] = cvt_pk_bf16(fmaxf(o[2 * q], 0.f), fmaxf(o[2 * q + 1], 0.f));
    uint2v s02 = __builtin_amdgcn_permlane32_swap(W[0], W[2], false, false);
    uint2v s13 = __builtin_amdgcn_permlane32_swap(W[1], W[3], false, false);
    uint2v s46 = __builtin_amdgcn_permlane32_swap(W[4], W[6], false, false);
    uint2v s57 = __builtin_amdgcn_permlane32_swap(W[5], W[7], false, false);
    uint4v f0 = {s02[0], s13[0], s02[1], s13[1]};
    uint4v f1 = {s46[0], s57[0], s46[1], s57[1]};
    short8 af0 = __builtin_bit_cast(short8, f0);
    short8 af1 = __builtin_bit_cast(short8, f1);

    // mm2: 4 gene quads, ksteps 2jt (af0, chunks 0-3) / 2jt+1 (af1, 4-7)
    acc0 = __builtin_amdgcn_mfma_f32_32x32x16_bf16(af0, wB[256 + l], acc0, 0, 0, 0);
    acc1 = __builtin_amdgcn_mfma_f32_32x32x16_bf16(af0, wB[320 + l], acc1, 0, 0, 0);
    acc2 = __builtin_amdgcn_mfma_f32_32x32x16_bf16(af0, wB[384 + l], acc2, 0, 0, 0);
    acc3 = __builtin_amdgcn_mfma_f32_32x32x16_bf16(af0, wB[448 + l], acc3, 0, 0, 0);
    acc0 = __builtin_amdgcn_mfma_f32_32x32x16_bf16(af1, wB[512 + l], acc0, 0, 0, 0);
    acc1 = __builtin_amdgcn_mfma_f32_32x32x16_bf16(af1, wB[576 + l], acc1, 0, 0, 0);
    acc2 = __builtin_amdgcn_mfma_f32_32x32x16_bf16(af1, wB[640 + l], acc2, 0, 0, 0);
    acc3 = __builtin_amdgcn_mfma_f32_32x32x16_bf16(af1, wB[704 + l], acc3, 0, 0, 0);
  }

  // hoisted bias per gene quad
  float br0 = b_reg[m];
  float br1 = b_reg[32 + m];
  float br2 = b_reg[64 + m];
  float br3 = (96 + m < 117) ? b_reg[96 + m] : 0.f;

  // ---- spot from registers: per quad, sum relu over this wave's 32 cells
  {
    auto rsum = [&](const f32x16& A, float br) {
      float s = 0.f;
      #pragma unroll
      for (int reg = 0; reg < 16; ++reg) s += fmaxf(A[reg] + br + gb, 0.f);
      s += __shfl_xor(s, 32, 64);
      return s;
    };
    float s0 = rsum(acc0, br0);
    float s1 = rsum(acc1, br1);
    float s2 = rsum(acc2, br2);
    float s3 = rsum(acc3, br3);
    if (hh == 0) {
      redp[wct * 128 + m] = s0;
      redp[wct * 128 + 32 + m] = s1;
      redp[wct * 128 + 64 + m] = s2;
      redp[wct * 128 + 96 + m] = s3;
    }
  }
  __syncthreads();   // redp complete (the ONLY epilogue barrier)
  if (tid < 117) {
    float s = 0.f;
    #pragma unroll
    for (int w = 0; w < 16; ++w) s += redp[w * 128 + tid];
    out[SPOT_OUT_OFF + b * 117 + tid] = s;
  }

  // ---- direct cell stores from accumulators (no LDS, no barriers) ----
  // row n = wct*32 + 4*hh + 8*G + rr; col g = q*32+m.
  bool q3ok = (m < 21);
  float* cbase = out + CELL_OUT_OFF + (rowbase + wct * 32 + 4 * hh) * 117 + m;
  #pragma unroll
  for (int G = 0; G < 4; ++G) {
    float* p = cbase + (8 * G) * 117;
    #pragma unroll
    for (int rr = 0; rr < 4; ++rr) {
      int r = G * 4 + rr;
      int ro = rr * 117;
      p[ro] = fmaxf(acc0[r] + br0 + gb, 0.f);
      p[ro + 32] = fmaxf(acc1[r] + br1 + gb, 0.f);
      p[ro + 64] = fmaxf(acc2[r] + br2 + gb, 0.f);
      if (q3ok) p[ro + 96] = fmaxf(acc3[r] + br3 + gb, 0.f);
    }
  }
}

extern "C" void kernel_launch(void* const* d_in, const int* in_sizes, int n_in,
                              void* d_out, int out_size, void* d_ws, size_t ws_size,
                              hipStream_t stream) {
  const float* images      = (const float*)d_in[0];
  const float* spot_images = (const float*)d_in[1];
  // d_in[2] = gene_expression (unused by the reference)
  const float* W_emph = (const float*)d_in[3];
  const float* b_emph = (const float*)d_in[4];
  const float* W_reg  = (const float*)d_in[5];
  const float* b_reg  = (const float*)d_in[6];
  const float* W_patch = (const float*)d_in[7];
  const float* b_patch = (const float*)d_in[8];
  const float* W_glob  = (const float*)d_in[9];
  const float* b_glob  = (const float*)d_in[10];
  float* out = (float*)d_out;

  unsigned short* wcomb = (unsigned short*)((char*)d_ws + WCOMB_OFF);
  float* glob  = (float*)((char*)d_ws + GLOB_OFF);

  prep_kernel<<<496, 128, 0, stream>>>(spot_images, W_patch, b_patch, W_glob,
                                       b_glob, W_reg, W_emph, b_emph, wcomb,
                                       glob);
  main_kernel<<<256, 1024, 0, stream>>>(images, b_reg, wcomb, glob, out);
}